// Round 14
// baseline (1206.038 us; speedup 1.0000x reference)
//
#include <hip/hip_runtime.h>

typedef unsigned short u16;
typedef unsigned int u32;
typedef __attribute__((ext_vector_type(8))) short bf16x8;
typedef __attribute__((ext_vector_type(4))) float f32x4;

#define T_STEPS 512
#define FEAT 128
#define H1 200
#define G1P 832             // 4 gates x 208 padded cols
#define XG_T_BYTES 425984   // 256 * 832 * 2
#define XG_ROW_BYTES 1664   // 832 * 2

// async global->LDS, 16B/lane; LDS dest wave-uniform base (+lane*16 in HW)
#define G2L16(g, lp) __builtin_amdgcn_global_load_lds( \
    (const __attribute__((address_space(1))) void*)(g), \
    (__attribute__((address_space(3))) void*)(lp), 16, 0, 0)

__device__ __forceinline__ u16 f2bf(float x) {
    u32 u = __float_as_uint(x);
    u = (u + 0x7fffu + ((u >> 16) & 1u)) >> 16;
    return (u16)u;
}
__device__ __forceinline__ float bfu2f(u32 u) { return __uint_as_float(u << 16); }

__device__ __forceinline__ float sig2(float x) {
    return __builtin_amdgcn_rcpf(1.f + __builtin_amdgcn_exp2f(-1.442695041f * x));
}
__device__ __forceinline__ float tanh2(float x) {
    return 1.f - 2.f * __builtin_amdgcn_rcpf(1.f + __builtin_amdgcn_exp2f(2.885390082f * x));
}

// ---------------------------------------------------------------------------
// Kernel 1: repack to bf16 B-fragment order in PADDED column space
// (r11/r13-verified verbatim). col' in [0,832): gate g = col'/208, j = col'%208;
// raw row = g*200+j (0 for j>=200). whhf: 52 tiles [tile*7+kt][lane][8].
// ---------------------------------------------------------------------------
__global__ void repack_k(const float* __restrict__ wih1, const float* __restrict__ whh1,
                         const float* __restrict__ bih1, const float* __restrict__ bhh1,
                         u16* __restrict__ wihf, u16* __restrict__ whhf, float* __restrict__ b1p) {
    int id = blockIdx.x * 256 + threadIdx.x;
    if (id < G1P) {
        int g = id / 208, j = id - g * 208;
        b1p[id] = (j < H1) ? (bih1[g * H1 + j] + bhh1[g * H1 + j]) : 0.f;
    }
    if (id < 23296) { // 52*7*64 lane-slots for whh
        int l = id & 63, fi = id >> 6;
        int kt = fi % 7, tile = fi / 7;
        int g = tile / 13, jt = tile - g * 13;
        int j = jt * 16 + (l & 15);
        int kb = kt * 32 + (l >> 4) * 8;
        u16 o[8];
#pragma unroll
        for (int jj = 0; jj < 8; ++jj) {
            int k = kb + jj;
            float v = (j < H1 && k < H1) ? whh1[(g * H1 + j) * H1 + k] : 0.f;
            o[jj] = f2bf(v);
        }
        uint4 pk;
        pk.x = (u32)o[0] | ((u32)o[1] << 16);
        pk.y = (u32)o[2] | ((u32)o[3] << 16);
        pk.z = (u32)o[4] | ((u32)o[5] << 16);
        pk.w = (u32)o[6] | ((u32)o[7] << 16);
        *(uint4*)(whhf + (size_t)id * 8) = pk;
    }
    int id2 = id - 23296;
    if (id2 >= 0 && id2 < 13312) { // 52*4*64 lane-slots for wih
        int l = id2 & 63, fi = id2 >> 6;
        int kt = fi & 3, tile = fi >> 2;
        int g = tile / 13, jt = tile - g * 13;
        int j = jt * 16 + (l & 15);
        int kb = kt * 32 + (l >> 4) * 8;
        u16 o[8];
#pragma unroll
        for (int jj = 0; jj < 8; ++jj) {
            int k = kb + jj;
            float v = (j < H1) ? wih1[(g * H1 + j) * FEAT + k] : 0.f;
            o[jj] = f2bf(v);
        }
        uint4 pk;
        pk.x = (u32)o[0] | ((u32)o[1] << 16);
        pk.y = (u32)o[2] | ((u32)o[3] << 16);
        pk.z = (u32)o[4] | ((u32)o[5] << 16);
        pk.w = (u32)o[6] | ((u32)o[7] << 16);
        *(uint4*)(wihf + (size_t)id2 * 8) = pk;
    }
}

// ---------------------------------------------------------------------------
// Kernel 2: xg = X @ W_ih1^T + bias, bf16, xg[t][b][col' 0..831] padded space
// (r11/r13-verified verbatim)
// ---------------------------------------------------------------------------
__global__ __launch_bounds__(256, 1) void xg_gemm(const float* __restrict__ X,
                                                  const u16* __restrict__ wihf,
                                                  const float* __restrict__ b1p,
                                                  u16* __restrict__ xg) {
    __shared__ u16 xs[64 * 128];
    int tid = threadIdx.x, wg = blockIdx.x;
    int l = tid & 63, wv = tid >> 6;
    int arow = l & 15, khi = l >> 4;

    const float4* Xv = (const float4*)(X + (size_t)wg * 64 * 128);
#pragma unroll
    for (int i = 0; i < 8; ++i) {
        int idx = tid + i * 256;
        float4 v = Xv[idx];
        int row = idx >> 5;
        int col = (idx & 31) * 4;
        uint2 pk;
        pk.x = (u32)f2bf(v.x) | ((u32)f2bf(v.y) << 16);
        pk.y = (u32)f2bf(v.z) | ((u32)f2bf(v.w) << 16);
        int byteo = (row * 256 + col * 2) ^ ((row & 7) << 4);
        *(uint2*)((char*)xs + byteo) = pk;
    }
    __syncthreads();

    f32x4 acc[4][13];
#pragma unroll
    for (int mt = 0; mt < 4; ++mt)
#pragma unroll
        for (int nt = 0; nt < 13; ++nt) acc[mt][nt] = (f32x4){0.f, 0.f, 0.f, 0.f};

#pragma unroll
    for (int kt = 0; kt < 4; ++kt) {
        bf16x8 wfr[13];
#pragma unroll
        for (int nt = 0; nt < 13; ++nt) {
            int ntg = wv * 13 + nt;
            wfr[nt] = *(const bf16x8*)(wihf + ((size_t)(ntg * 4 + kt) * 64 + l) * 8);
        }
#pragma unroll
        for (int mt = 0; mt < 4; ++mt) {
            int row = mt * 16 + arow;
            int byteo = (row * 256 + kt * 64 + khi * 16) ^ ((row & 7) << 4);
            bf16x8 a = *(const bf16x8*)((const char*)xs + byteo);
#pragma unroll
            for (int nt = 0; nt < 13; ++nt)
                acc[mt][nt] = __builtin_amdgcn_mfma_f32_16x16x32_bf16(a, wfr[nt], acc[mt][nt], 0, 0, 0);
        }
    }

    int t = wg >> 2;
#pragma unroll
    for (int nt = 0; nt < 13; ++nt) {
        int ntg = wv * 13 + nt;
        int colg = ntg * 16 + arow;
        float bias = b1p[colg];
#pragma unroll
        for (int mt = 0; mt < 4; ++mt) {
#pragma unroll
            for (int r = 0; r < 4; ++r) {
                int bg = (wg & 3) * 64 + mt * 16 + khi * 4 + r;
                xg[((size_t)t * 256 + bg) * G1P + colg] = f2bf(acc[mt][nt][r] + bias);
            }
        }
    }
}

// ---------------------------------------------------------------------------
// Kernel 3: persistent fused 2-layer LSTM. 256 WGs x 896 threads (14 waves,
// 1 WG/CU -> ~146 unified regs/wave). Waves 0-12: ONE gate-column group each
// (4 tiles = 112 wf regs -> fits the ARCH file: no AGPR copies, no spill).
// Wave 13: xg stager + layer-2. In-register EW (r13), broadcast h reads,
// 1 barrier/step. All MFMA intrinsic.
// ---------------------------------------------------------------------------
#define LDHB(KT) (*(const bf16x8*)(hbr + (KT) * 64 + khi * 16))

template<int MODE>  // 0 = group-wave, 1 = stager + layer-2 wave
__device__ __forceinline__ void lstm_body(
    int g0, int l, int mw,
    const u16* __restrict__ xg, const u16* __restrict__ whhf,
    const float* __restrict__ w_ih2, const float* __restrict__ w_hh2,
    const float* __restrict__ b_ih2, const float* __restrict__ b_hh2,
    float* __restrict__ out, u16* hbuf, u16* xgs)
{
    const int arow = l & 15, khi = l >> 4;
    const f32x4 fz = {0.f, 0.f, 0.f, 0.f};

    // MODE 0: one group's 4 tiles {g0, g0+13, g0+26, g0+39} in registers
    bf16x8 wf[4][7];
    if constexpr (MODE == 0) {
#pragma unroll
        for (int gt = 0; gt < 4; ++gt) {
            int tile = g0 + 13 * gt;
#pragma unroll
            for (int kt = 0; kt < 7; ++kt)
                wf[gt][kt] = *(const bf16x8*)(whhf + ((size_t)(tile * 7 + kt) * 64 + l) * 8);
        }
    }

    // MODE 1: layer-2 weights + state (r13-verified)
    bf16x8 wf2[7];
    float wh[4][3], b2l[4];
    float h2p = 0.f, c2 = 0.f;
    f32x4 acc2 = fz;
    if constexpr (MODE == 1) {
#pragma unroll
        for (int kt = 0; kt < 7; ++kt) {
            u16 o[8];
#pragma unroll
            for (int jj = 0; jj < 8; ++jj) {
                int k = kt * 32 + khi * 8 + jj;
                o[jj] = (arow < 12 && k < H1) ? f2bf(w_ih2[arow * H1 + k]) : (u16)0;
            }
            uint4 pk;
            pk.x = (u32)o[0] | ((u32)o[1] << 16);
            pk.y = (u32)o[2] | ((u32)o[3] << 16);
            pk.z = (u32)o[4] | ((u32)o[5] << 16);
            pk.w = (u32)o[6] | ((u32)o[7] << 16);
            wf2[kt] = *(bf16x8*)&pk;
        }
        int hs = (l < 3) ? l : 0;
#pragma unroll
        for (int g = 0; g < 4; ++g) {
#pragma unroll
            for (int q = 0; q < 3; ++q) wh[g][q] = w_hh2[(g * 3 + hs) * 3 + q];
            b2l[g] = b_ih2[g * 3 + hs] + b_hh2[g * 3 + hs];
        }
    }

    float creg = 0.f;

    auto L2EW = [&](int tout) {
        int hs = (l < 3) ? l : 0;
        float pi = __shfl(acc2[0], hs);
        float pf = __shfl(acc2[0], 3 + hs);
        float pg = __shfl(acc2[0], 6 + hs);
        float po = __shfl(acc2[0], 9 + hs);
        float hq0 = __shfl(h2p, 0);
        float hq1 = __shfl(h2p, 1);
        float hq2 = __shfl(h2p, 2);
        pi += b2l[0] + wh[0][0] * hq0 + wh[0][1] * hq1 + wh[0][2] * hq2;
        pf += b2l[1] + wh[1][0] * hq0 + wh[1][1] * hq1 + wh[1][2] * hq2;
        pg += b2l[2] + wh[2][0] * hq0 + wh[2][1] * hq1 + wh[2][2] * hq2;
        po += b2l[3] + wh[3][0] * hq0 + wh[3][1] * hq1 + wh[3][2] * hq2;
        float gi = sig2(pi), gf = sig2(pf), gg2 = tanh2(pg), go = sig2(po);
        c2 = gf * c2 + gi * gg2;
        h2p = go * tanh2(c2);
        if (l < 3) out[(size_t)tout * 768 + mw * 3 + l] = h2p;
    };

    // stager: whole 1664-B xg row, 2 x G2L16 (64 + 40 lanes)
    const char* sp = (const char*)xg + (size_t)mw * XG_ROW_BYTES;
    if constexpr (MODE == 1) {
        char* d = (char*)xgs;  // buf 0 (t=0)
        G2L16(sp + (size_t)l * 16, d);
        if (l < 40) G2L16(sp + 1024 + (size_t)l * 16, d + 1024);
        sp += XG_T_BYTES;
        asm volatile("s_waitcnt vmcnt(0)" ::: "memory");
    }
    __syncthreads();

    for (int t = 0; t < T_STEPS; ++t) {
        const char* hbr = (const char*)(hbuf + (t & 1) * 224);
        u16* hbw = hbuf + ((t + 1) & 1) * 224;
        const u16* xr = xgs + (t & 1) * 832;

        if constexpr (MODE == 1) {
            // stage xg(t+1) early; drained by vmcnt(0) before this step's barrier
            char* d = (char*)xgs + ((t + 1) & 1) * 1664;
            G2L16(sp + (size_t)l * 16, d);
            if (l < 40) G2L16(sp + 1024 + (size_t)l * 16, d + 1024);
            sp += XG_T_BYTES;
            if (t >= 2) L2EW(t - 2); // consumes prev-iteration acc2

            bf16x8 ha0 = LDHB(0), ha1 = LDHB(1);
            acc2 = __builtin_amdgcn_mfma_f32_16x16x32_bf16(ha0, wf2[0], fz, 0, 0, 0);
            ha0 = LDHB(2);
            acc2 = __builtin_amdgcn_mfma_f32_16x16x32_bf16(ha1, wf2[1], acc2, 0, 0, 0);
            ha1 = LDHB(3);
            acc2 = __builtin_amdgcn_mfma_f32_16x16x32_bf16(ha0, wf2[2], acc2, 0, 0, 0);
            ha0 = LDHB(4);
            acc2 = __builtin_amdgcn_mfma_f32_16x16x32_bf16(ha1, wf2[3], acc2, 0, 0, 0);
            ha1 = LDHB(5);
            acc2 = __builtin_amdgcn_mfma_f32_16x16x32_bf16(ha0, wf2[4], acc2, 0, 0, 0);
            ha0 = LDHB(6);
            acc2 = __builtin_amdgcn_mfma_f32_16x16x32_bf16(ha1, wf2[5], acc2, 0, 0, 0);
            acc2 = __builtin_amdgcn_mfma_f32_16x16x32_bf16(ha0, wf2[6], acc2, 0, 0, 0);

            asm volatile("s_waitcnt vmcnt(0)" ::: "memory"); // xg(t+1) landed
        } else {
            bf16x8 ha0 = LDHB(0), ha1 = LDHB(1);
            f32x4 acc[4];
#pragma unroll
            for (int gt = 0; gt < 4; ++gt)
                acc[gt] = __builtin_amdgcn_mfma_f32_16x16x32_bf16(ha0, wf[gt][0], fz, 0, 0, 0);
            ha0 = LDHB(2);
#pragma unroll
            for (int gt = 0; gt < 4; ++gt)
                acc[gt] = __builtin_amdgcn_mfma_f32_16x16x32_bf16(ha1, wf[gt][1], acc[gt], 0, 0, 0);
            ha1 = LDHB(3);
#pragma unroll
            for (int gt = 0; gt < 4; ++gt)
                acc[gt] = __builtin_amdgcn_mfma_f32_16x16x32_bf16(ha0, wf[gt][2], acc[gt], 0, 0, 0);
            ha0 = LDHB(4);
#pragma unroll
            for (int gt = 0; gt < 4; ++gt)
                acc[gt] = __builtin_amdgcn_mfma_f32_16x16x32_bf16(ha1, wf[gt][3], acc[gt], 0, 0, 0);
            ha1 = LDHB(5);
#pragma unroll
            for (int gt = 0; gt < 4; ++gt)
                acc[gt] = __builtin_amdgcn_mfma_f32_16x16x32_bf16(ha0, wf[gt][4], acc[gt], 0, 0, 0);
            ha0 = LDHB(6);
#pragma unroll
            for (int gt = 0; gt < 4; ++gt)
                acc[gt] = __builtin_amdgcn_mfma_f32_16x16x32_bf16(ha1, wf[gt][5], acc[gt], 0, 0, 0);
#pragma unroll
            for (int gt = 0; gt < 4; ++gt)
                acc[gt] = __builtin_amdgcn_mfma_f32_16x16x32_bf16(ha0, wf[gt][6], acc[gt], 0, 0, 0);

            // in-register elementwise: lanes 0-15 hold row 0 (r13-verified)
            if (l < 16) {
                int j = g0 * 16 + l; // hidden col in padded [0,208)
                float pi = acc[0][0] + bfu2f(xr[j]);
                float pf = acc[1][0] + bfu2f(xr[208 + j]);
                float pg = acc[2][0] + bfu2f(xr[416 + j]);
                float po = acc[3][0] + bfu2f(xr[624 + j]);
                float gi = sig2(pi), gf = sig2(pf), gv = tanh2(pg), go = sig2(po);
                float c = gf * creg + gi * gv;
                creg = c;
                hbw[j] = f2bf(go * tanh2(c)); // pad cols j>=200 harmless (K-pad weights 0)
            }
        }

        asm volatile("s_waitcnt lgkmcnt(0)" ::: "memory");
        __builtin_amdgcn_s_barrier(); // single barrier per step
    }

    asm volatile("s_waitcnt vmcnt(0)" ::: "memory"); // drain dangling t=512 stage

    // epilogue (wave 13): layer-2 for steps 510 and 511 (r13-verified)
    if constexpr (MODE == 1) {
        L2EW(510);
        const char* hbr = (const char*)(hbuf + (T_STEPS & 1) * 224); // h(511)
        bf16x8 he = LDHB(0);
        acc2 = __builtin_amdgcn_mfma_f32_16x16x32_bf16(he, wf2[0], fz, 0, 0, 0);
#pragma unroll
        for (int kt = 1; kt < 7; ++kt) {
            he = LDHB(kt);
            acc2 = __builtin_amdgcn_mfma_f32_16x16x32_bf16(he, wf2[kt], acc2, 0, 0, 0);
        }
        L2EW(511);
    }
}

__global__ __launch_bounds__(896, 1)
void lstm_main(const u16* __restrict__ xg,
               const u16* __restrict__ whhf,
               const float* __restrict__ w_ih2,
               const float* __restrict__ w_hh2,
               const float* __restrict__ b_ih2,
               const float* __restrict__ b_hh2,
               float* __restrict__ out) {
    __shared__ __align__(16) u16 hbuf[2 * 224];   //   896 B, dbuf'd h (row 0 only)
    __shared__ __align__(16) u16 xgs[2 * 832];    //  3328 B, staged xg (dbuf)
    __shared__ char ldspad[84000];                // forces 1 WG/CU

    int tid = threadIdx.x, mw = blockIdx.x;
    int l = tid & 63, wv = tid >> 6;

    for (int i = tid; i < 448; i += 896) hbuf[i] = 0;
    if (tid < 84000) ((volatile char*)ldspad)[tid] = 0; // keep pad alive

    // waves 0-12: gate-column groups 0-12; wave 13: stager + layer-2
    if (wv < 13)
        lstm_body<0>(wv, l, mw, xg, whhf, w_ih2, w_hh2, b_ih2, b_hh2, out, hbuf, xgs);
    else
        lstm_body<1>(0, l, mw, xg, whhf, w_ih2, w_hh2, b_ih2, b_hh2, out, hbuf, xgs);
}

extern "C" void kernel_launch(void* const* d_in, const int* in_sizes, int n_in,
                              void* d_out, int out_size, void* d_ws, size_t ws_size,
                              hipStream_t stream) {
    const float* X = (const float*)d_in[0];
    const float* w_ih1 = (const float*)d_in[1];
    const float* w_hh1 = (const float*)d_in[2];
    const float* b_ih1 = (const float*)d_in[3];
    const float* b_hh1 = (const float*)d_in[4];
    const float* w_ih2 = (const float*)d_in[5];
    const float* w_hh2 = (const float*)d_in[6];
    const float* b_ih2 = (const float*)d_in[7];
    const float* b_hh2 = (const float*)d_in[8];
    float* out = (float*)d_out;

    char* ws = (char*)d_ws;
    size_t off = 0;
    u16* xg = (u16*)(ws + off);
    off += (size_t)512 * 256 * G1P * 2; // 218,103,808 B
    u16* whhf = (u16*)(ws + off);
    off += (size_t)23296 * 8 * 2; // 372,736 B (also absorbs t=512 stage overread)
    u16* wihf = (u16*)(ws + off);
    off += (size_t)13312 * 8 * 2; // 212,992 B
    float* b1p = (float*)(ws + off);
    off += G1P * 4;
    if (ws_size < off) return; // insufficient workspace -> visible failure

    repack_k<<<143, 256, 0, stream>>>(w_ih1, w_hh1, b_ih1, b_hh1, wihf, whhf, b1p);
    xg_gemm<<<2048, 256, 0, stream>>>(X, wihf, b1p, xg);
    lstm_main<<<256, 896, 0, stream>>>(xg, whhf, w_ih2, w_hh2, b_ih2, b_hh2, out);
}

// Round 15
// 686.737 us; speedup vs baseline: 1.7562x; 1.7562x over previous
//
#include <hip/hip_runtime.h>

typedef unsigned short u16;
typedef unsigned int u32;
typedef __attribute__((ext_vector_type(8))) short bf16x8;
typedef __attribute__((ext_vector_type(4))) float f32x4;

#define T_STEPS 512
#define FEAT 128
#define H1 200
#define G1P 832             // 4 gates x 208 padded cols
#define XG_T_BYTES 425984   // 256 * 832 * 2
#define XG_ROW_BYTES 1664   // 832 * 2

// async global->LDS, 16B/lane; LDS dest wave-uniform base (+lane*16 in HW)
#define G2L16(g, lp) __builtin_amdgcn_global_load_lds( \
    (const __attribute__((address_space(1))) void*)(g), \
    (__attribute__((address_space(3))) void*)(lp), 16, 0, 0)

__device__ __forceinline__ u16 f2bf(float x) {
    u32 u = __float_as_uint(x);
    u = (u + 0x7fffu + ((u >> 16) & 1u)) >> 16;
    return (u16)u;
}
__device__ __forceinline__ float bfu2f(u32 u) { return __uint_as_float(u << 16); }

__device__ __forceinline__ float sig2(float x) {
    return __builtin_amdgcn_rcpf(1.f + __builtin_amdgcn_exp2f(-1.442695041f * x));
}
__device__ __forceinline__ float tanh2(float x) {
    return 1.f - 2.f * __builtin_amdgcn_rcpf(1.f + __builtin_amdgcn_exp2f(2.885390082f * x));
}

// ---------------------------------------------------------------------------
// Kernel 1: repack to bf16 B-fragment order in PADDED column space
// (r11/r13-verified verbatim). col' in [0,832): gate g = col'/208, j = col'%208;
// raw row = g*200+j (0 for j>=200). whhf: 52 tiles [tile*7+kt][lane][8].
// ---------------------------------------------------------------------------
__global__ void repack_k(const float* __restrict__ wih1, const float* __restrict__ whh1,
                         const float* __restrict__ bih1, const float* __restrict__ bhh1,
                         u16* __restrict__ wihf, u16* __restrict__ whhf, float* __restrict__ b1p) {
    int id = blockIdx.x * 256 + threadIdx.x;
    if (id < G1P) {
        int g = id / 208, j = id - g * 208;
        b1p[id] = (j < H1) ? (bih1[g * H1 + j] + bhh1[g * H1 + j]) : 0.f;
    }
    if (id < 23296) { // 52*7*64 lane-slots for whh
        int l = id & 63, fi = id >> 6;
        int kt = fi % 7, tile = fi / 7;
        int g = tile / 13, jt = tile - g * 13;
        int j = jt * 16 + (l & 15);
        int kb = kt * 32 + (l >> 4) * 8;
        u16 o[8];
#pragma unroll
        for (int jj = 0; jj < 8; ++jj) {
            int k = kb + jj;
            float v = (j < H1 && k < H1) ? whh1[(g * H1 + j) * H1 + k] : 0.f;
            o[jj] = f2bf(v);
        }
        uint4 pk;
        pk.x = (u32)o[0] | ((u32)o[1] << 16);
        pk.y = (u32)o[2] | ((u32)o[3] << 16);
        pk.z = (u32)o[4] | ((u32)o[5] << 16);
        pk.w = (u32)o[6] | ((u32)o[7] << 16);
        *(uint4*)(whhf + (size_t)id * 8) = pk;
    }
    int id2 = id - 23296;
    if (id2 >= 0 && id2 < 13312) { // 52*4*64 lane-slots for wih
        int l = id2 & 63, fi = id2 >> 6;
        int kt = fi & 3, tile = fi >> 2;
        int g = tile / 13, jt = tile - g * 13;
        int j = jt * 16 + (l & 15);
        int kb = kt * 32 + (l >> 4) * 8;
        u16 o[8];
#pragma unroll
        for (int jj = 0; jj < 8; ++jj) {
            int k = kb + jj;
            float v = (j < H1) ? wih1[(g * H1 + j) * FEAT + k] : 0.f;
            o[jj] = f2bf(v);
        }
        uint4 pk;
        pk.x = (u32)o[0] | ((u32)o[1] << 16);
        pk.y = (u32)o[2] | ((u32)o[3] << 16);
        pk.z = (u32)o[4] | ((u32)o[5] << 16);
        pk.w = (u32)o[6] | ((u32)o[7] << 16);
        *(uint4*)(wihf + (size_t)id2 * 8) = pk;
    }
}

// ---------------------------------------------------------------------------
// Kernel 2: xg = X @ W_ih1^T + bias, bf16, xg[t][b][col' 0..831] padded space
// (r11/r13-verified verbatim)
// ---------------------------------------------------------------------------
__global__ __launch_bounds__(256, 1) void xg_gemm(const float* __restrict__ X,
                                                  const u16* __restrict__ wihf,
                                                  const float* __restrict__ b1p,
                                                  u16* __restrict__ xg) {
    __shared__ u16 xs[64 * 128];
    int tid = threadIdx.x, wg = blockIdx.x;
    int l = tid & 63, wv = tid >> 6;
    int arow = l & 15, khi = l >> 4;

    const float4* Xv = (const float4*)(X + (size_t)wg * 64 * 128);
#pragma unroll
    for (int i = 0; i < 8; ++i) {
        int idx = tid + i * 256;
        float4 v = Xv[idx];
        int row = idx >> 5;
        int col = (idx & 31) * 4;
        uint2 pk;
        pk.x = (u32)f2bf(v.x) | ((u32)f2bf(v.y) << 16);
        pk.y = (u32)f2bf(v.z) | ((u32)f2bf(v.w) << 16);
        int byteo = (row * 256 + col * 2) ^ ((row & 7) << 4);
        *(uint2*)((char*)xs + byteo) = pk;
    }
    __syncthreads();

    f32x4 acc[4][13];
#pragma unroll
    for (int mt = 0; mt < 4; ++mt)
#pragma unroll
        for (int nt = 0; nt < 13; ++nt) acc[mt][nt] = (f32x4){0.f, 0.f, 0.f, 0.f};

#pragma unroll
    for (int kt = 0; kt < 4; ++kt) {
        bf16x8 wfr[13];
#pragma unroll
        for (int nt = 0; nt < 13; ++nt) {
            int ntg = wv * 13 + nt;
            wfr[nt] = *(const bf16x8*)(wihf + ((size_t)(ntg * 4 + kt) * 64 + l) * 8);
        }
#pragma unroll
        for (int mt = 0; mt < 4; ++mt) {
            int row = mt * 16 + arow;
            int byteo = (row * 256 + kt * 64 + khi * 16) ^ ((row & 7) << 4);
            bf16x8 a = *(const bf16x8*)((const char*)xs + byteo);
#pragma unroll
            for (int nt = 0; nt < 13; ++nt)
                acc[mt][nt] = __builtin_amdgcn_mfma_f32_16x16x32_bf16(a, wfr[nt], acc[mt][nt], 0, 0, 0);
        }
    }

    int t = wg >> 2;
#pragma unroll
    for (int nt = 0; nt < 13; ++nt) {
        int ntg = wv * 13 + nt;
        int colg = ntg * 16 + arow;
        float bias = b1p[colg];
#pragma unroll
        for (int mt = 0; mt < 4; ++mt) {
#pragma unroll
            for (int r = 0; r < 4; ++r) {
                int bg = (wg & 3) * 64 + mt * 16 + khi * 4 + r;
                xg[((size_t)t * 256 + bg) * G1P + colg] = f2bf(acc[mt][nt][r] + bias);
            }
        }
    }
}

// ---------------------------------------------------------------------------
// Kernel 3: persistent fused 2-layer LSTM. 256 WGs x 512 threads (8 waves,
// 2/SIMD even -> 256 unified regs/wave). Heavy waves w0-4: group A (4 reg
// tiles) + group B (2 reg + 2 LDS tiles) = 168 wf regs -> NO spill. Light:
// w5,w6 = 1 group + stage half-row; w7 = 1 group + layer-2. In-register EW
// (r13-verified), broadcast h reads, 1 barrier/step. All MFMA intrinsic.
// ---------------------------------------------------------------------------
#define LDHB(KT) (*(const bf16x8*)(hbr + (KT) * 64 + khi * 16))
#define LDSW(S, KT) (*(const bf16x8*)((const char*)wlds + (size_t)((S) * 7 + (KT)) * 1024 + l * 16))

template<int MODE>  // 0 = heavy (2 groups, 2 LDS tiles), 1 = light + stager, 2 = light + L2
__device__ __forceinline__ void lstm_body(
    int g0A, int g0B, int slot0, int stgoff, int l, int mw,
    const u16* __restrict__ xg, const u16* __restrict__ whhf,
    const float* __restrict__ w_ih2, const float* __restrict__ w_hh2,
    const float* __restrict__ b_ih2, const float* __restrict__ b_hh2,
    float* __restrict__ out, u16* hbuf, u16* xgs, const u16* wlds)
{
    constexpr int NT = (MODE == 0) ? 6 : 4;  // register-resident tiles
    const int arow = l & 15, khi = l >> 4;
    const f32x4 fz = {0.f, 0.f, 0.f, 0.f};

    // register tiles: nt<4 -> group A gates 0-3; nt>=4 -> group B gates 0,1
    bf16x8 wf[NT][7];
#pragma unroll
    for (int nt = 0; nt < NT; ++nt) {
        int tile = (nt < 4) ? g0A + 13 * nt : g0B + 13 * (nt - 4);
#pragma unroll
        for (int kt = 0; kt < 7; ++kt)
            wf[nt][kt] = *(const bf16x8*)(whhf + ((size_t)(tile * 7 + kt) * 64 + l) * 8);
    }

    // layer-2 weights + state (wave 7 only; r13-verified)
    bf16x8 wf2[7];
    float wh[4][3], b2l[4];
    float h2p = 0.f, c2 = 0.f;
    f32x4 acc2 = fz;
    if constexpr (MODE == 2) {
#pragma unroll
        for (int kt = 0; kt < 7; ++kt) {
            u16 o[8];
#pragma unroll
            for (int jj = 0; jj < 8; ++jj) {
                int k = kt * 32 + khi * 8 + jj;
                o[jj] = (arow < 12 && k < H1) ? f2bf(w_ih2[arow * H1 + k]) : (u16)0;
            }
            uint4 pk;
            pk.x = (u32)o[0] | ((u32)o[1] << 16);
            pk.y = (u32)o[2] | ((u32)o[3] << 16);
            pk.z = (u32)o[4] | ((u32)o[5] << 16);
            pk.w = (u32)o[6] | ((u32)o[7] << 16);
            wf2[kt] = *(bf16x8*)&pk;
        }
        int hs = (l < 3) ? l : 0;
#pragma unroll
        for (int g = 0; g < 4; ++g) {
#pragma unroll
            for (int q = 0; q < 3; ++q) wh[g][q] = w_hh2[(g * 3 + hs) * 3 + q];
            b2l[g] = b_ih2[g * 3 + hs] + b_hh2[g * 3 + hs];
        }
    }

    float cregA = 0.f, cregB = 0.f;

    auto L2EW = [&](int tout) {
        int hs = (l < 3) ? l : 0;
        float pi = __shfl(acc2[0], hs);
        float pf = __shfl(acc2[0], 3 + hs);
        float pg = __shfl(acc2[0], 6 + hs);
        float po = __shfl(acc2[0], 9 + hs);
        float hq0 = __shfl(h2p, 0);
        float hq1 = __shfl(h2p, 1);
        float hq2 = __shfl(h2p, 2);
        pi += b2l[0] + wh[0][0] * hq0 + wh[0][1] * hq1 + wh[0][2] * hq2;
        pf += b2l[1] + wh[1][0] * hq0 + wh[1][1] * hq1 + wh[1][2] * hq2;
        pg += b2l[2] + wh[2][0] * hq0 + wh[2][1] * hq1 + wh[2][2] * hq2;
        po += b2l[3] + wh[3][0] * hq0 + wh[3][1] * hq1 + wh[3][2] * hq2;
        float gi = sig2(pi), gf = sig2(pf), gg2 = tanh2(pg), go = sig2(po);
        c2 = gf * c2 + gi * gg2;
        h2p = go * tanh2(c2);
        if (l < 3) out[(size_t)tout * 768 + mw * 3 + l] = h2p;
    };

    // stager (MODE 1): one half-row = 832 B = 52 lanes x 16 B
    const char* sp = (const char*)xg + (size_t)mw * XG_ROW_BYTES + stgoff;
    if constexpr (MODE == 1) {
        char* d = (char*)xgs + stgoff;  // buf 0 (t=0)
        if (l < 52) G2L16(sp + (size_t)l * 16, d);
        sp += XG_T_BYTES;
        asm volatile("s_waitcnt vmcnt(0)" ::: "memory");
    }
    __syncthreads();

    for (int t = 0; t < T_STEPS; ++t) {
        const char* hbr = (const char*)(hbuf + (t & 1) * 224);
        u16* hbw = hbuf + ((t + 1) & 1) * 224;
        const u16* xr = xgs + (t & 1) * 832;

        if constexpr (MODE == 1) { // stage xg(t+1) early; drained before barrier
            char* d = (char*)xgs + ((t + 1) & 1) * 1664 + stgoff;
            if (l < 52) G2L16(sp + (size_t)l * 16, d);
            sp += XG_T_BYTES;
        }
        if constexpr (MODE == 2) {
            if (t >= 2) L2EW(t - 2); // consumes prev-iteration acc2
        }

        // MFMA chain, ha 2-deep rotation; LDS B-tiles (heavy) 1-kt prefetch
        bf16x8 ha0 = LDHB(0), ha1 = LDHB(1);
        bf16x8 wA0, wB0, wA1, wB1;
        if constexpr (MODE == 0) { wA0 = LDSW(slot0, 0); wB0 = LDSW(slot0 + 1, 0); }

        f32x4 acc[NT], aL0, aL1;
        // kt = 0 (ha0 / w*0)
#pragma unroll
        for (int nt = 0; nt < NT; ++nt)
            acc[nt] = __builtin_amdgcn_mfma_f32_16x16x32_bf16(ha0, wf[nt][0], fz, 0, 0, 0);
        if constexpr (MODE == 0) {
            aL0 = __builtin_amdgcn_mfma_f32_16x16x32_bf16(ha0, wA0, fz, 0, 0, 0);
            aL1 = __builtin_amdgcn_mfma_f32_16x16x32_bf16(ha0, wB0, fz, 0, 0, 0);
            wA1 = LDSW(slot0, 1); wB1 = LDSW(slot0 + 1, 1);
        }
        if constexpr (MODE == 2) acc2 = __builtin_amdgcn_mfma_f32_16x16x32_bf16(ha0, wf2[0], fz, 0, 0, 0);
        ha0 = LDHB(2);
        // kt = 1 (ha1 / w*1)
#pragma unroll
        for (int nt = 0; nt < NT; ++nt)
            acc[nt] = __builtin_amdgcn_mfma_f32_16x16x32_bf16(ha1, wf[nt][1], acc[nt], 0, 0, 0);
        if constexpr (MODE == 0) {
            aL0 = __builtin_amdgcn_mfma_f32_16x16x32_bf16(ha1, wA1, aL0, 0, 0, 0);
            aL1 = __builtin_amdgcn_mfma_f32_16x16x32_bf16(ha1, wB1, aL1, 0, 0, 0);
            wA0 = LDSW(slot0, 2); wB0 = LDSW(slot0 + 1, 2);
        }
        if constexpr (MODE == 2) acc2 = __builtin_amdgcn_mfma_f32_16x16x32_bf16(ha1, wf2[1], acc2, 0, 0, 0);
        ha1 = LDHB(3);
        // kt = 2 (ha0 / w*0)
#pragma unroll
        for (int nt = 0; nt < NT; ++nt)
            acc[nt] = __builtin_amdgcn_mfma_f32_16x16x32_bf16(ha0, wf[nt][2], acc[nt], 0, 0, 0);
        if constexpr (MODE == 0) {
            aL0 = __builtin_amdgcn_mfma_f32_16x16x32_bf16(ha0, wA0, aL0, 0, 0, 0);
            aL1 = __builtin_amdgcn_mfma_f32_16x16x32_bf16(ha0, wB0, aL1, 0, 0, 0);
            wA1 = LDSW(slot0, 3); wB1 = LDSW(slot0 + 1, 3);
        }
        if constexpr (MODE == 2) acc2 = __builtin_amdgcn_mfma_f32_16x16x32_bf16(ha0, wf2[2], acc2, 0, 0, 0);
        ha0 = LDHB(4);
        // kt = 3 (ha1 / w*1)
#pragma unroll
        for (int nt = 0; nt < NT; ++nt)
            acc[nt] = __builtin_amdgcn_mfma_f32_16x16x32_bf16(ha1, wf[nt][3], acc[nt], 0, 0, 0);
        if constexpr (MODE == 0) {
            aL0 = __builtin_amdgcn_mfma_f32_16x16x32_bf16(ha1, wA1, aL0, 0, 0, 0);
            aL1 = __builtin_amdgcn_mfma_f32_16x16x32_bf16(ha1, wB1, aL1, 0, 0, 0);
            wA0 = LDSW(slot0, 4); wB0 = LDSW(slot0 + 1, 4);
        }
        if constexpr (MODE == 2) acc2 = __builtin_amdgcn_mfma_f32_16x16x32_bf16(ha1, wf2[3], acc2, 0, 0, 0);
        ha1 = LDHB(5);
        // kt = 4 (ha0 / w*0)
#pragma unroll
        for (int nt = 0; nt < NT; ++nt)
            acc[nt] = __builtin_amdgcn_mfma_f32_16x16x32_bf16(ha0, wf[nt][4], acc[nt], 0, 0, 0);
        if constexpr (MODE == 0) {
            aL0 = __builtin_amdgcn_mfma_f32_16x16x32_bf16(ha0, wA0, aL0, 0, 0, 0);
            aL1 = __builtin_amdgcn_mfma_f32_16x16x32_bf16(ha0, wB0, aL1, 0, 0, 0);
            wA1 = LDSW(slot0, 5); wB1 = LDSW(slot0 + 1, 5);
        }
        if constexpr (MODE == 2) acc2 = __builtin_amdgcn_mfma_f32_16x16x32_bf16(ha0, wf2[4], acc2, 0, 0, 0);
        ha0 = LDHB(6);
        // kt = 5 (ha1 / w*1)
#pragma unroll
        for (int nt = 0; nt < NT; ++nt)
            acc[nt] = __builtin_amdgcn_mfma_f32_16x16x32_bf16(ha1, wf[nt][5], acc[nt], 0, 0, 0);
        if constexpr (MODE == 0) {
            aL0 = __builtin_amdgcn_mfma_f32_16x16x32_bf16(ha1, wA1, aL0, 0, 0, 0);
            aL1 = __builtin_amdgcn_mfma_f32_16x16x32_bf16(ha1, wB1, aL1, 0, 0, 0);
            wA0 = LDSW(slot0, 6); wB0 = LDSW(slot0 + 1, 6);
        }
        if constexpr (MODE == 2) acc2 = __builtin_amdgcn_mfma_f32_16x16x32_bf16(ha1, wf2[5], acc2, 0, 0, 0);
        // kt = 6 (ha0 / w*0)
#pragma unroll
        for (int nt = 0; nt < NT; ++nt)
            acc[nt] = __builtin_amdgcn_mfma_f32_16x16x32_bf16(ha0, wf[nt][6], acc[nt], 0, 0, 0);
        if constexpr (MODE == 0) {
            aL0 = __builtin_amdgcn_mfma_f32_16x16x32_bf16(ha0, wA0, aL0, 0, 0, 0);
            aL1 = __builtin_amdgcn_mfma_f32_16x16x32_bf16(ha0, wB0, aL1, 0, 0, 0);
        }
        if constexpr (MODE == 2) acc2 = __builtin_amdgcn_mfma_f32_16x16x32_bf16(ha0, wf2[6], acc2, 0, 0, 0);

        // in-register elementwise (lanes 0-15, row 0; r13-verified)
        if (l < 16) {
            {
                int j = g0A * 16 + l;
                float pi = acc[0][0] + bfu2f(xr[j]);
                float pf = acc[1][0] + bfu2f(xr[208 + j]);
                float pg = acc[2][0] + bfu2f(xr[416 + j]);
                float po = acc[3][0] + bfu2f(xr[624 + j]);
                float gi = sig2(pi), gf = sig2(pf), gv = tanh2(pg), go = sig2(po);
                float c = gf * cregA + gi * gv;
                cregA = c;
                hbw[j] = f2bf(go * tanh2(c));
            }
            if constexpr (MODE == 0) {
                int j = g0B * 16 + l;
                float pi = acc[4][0] + bfu2f(xr[j]);
                float pf = acc[5][0] + bfu2f(xr[208 + j]);
                float pg = aL0[0] + bfu2f(xr[416 + j]);
                float po = aL1[0] + bfu2f(xr[624 + j]);
                float gi = sig2(pi), gf = sig2(pf), gv = tanh2(pg), go = sig2(po);
                float c = gf * cregB + gi * gv;
                cregB = c;
                hbw[j] = f2bf(go * tanh2(c));
            }
        }

        if constexpr (MODE == 1) asm volatile("s_waitcnt vmcnt(0)" ::: "memory"); // xg(t+1) landed
        asm volatile("s_waitcnt lgkmcnt(0)" ::: "memory");
        __builtin_amdgcn_s_barrier(); // single barrier per step
    }

    asm volatile("s_waitcnt vmcnt(0)" ::: "memory"); // drain dangling t=512 stage

    // epilogue (wave 7): layer-2 for steps 510 and 511 (r13-verified)
    if constexpr (MODE == 2) {
        L2EW(510);
        const char* hbr = (const char*)(hbuf + (T_STEPS & 1) * 224); // h(511)
        bf16x8 he = LDHB(0);
        acc2 = __builtin_amdgcn_mfma_f32_16x16x32_bf16(he, wf2[0], fz, 0, 0, 0);
#pragma unroll
        for (int kt = 1; kt < 7; ++kt) {
            he = LDHB(kt);
            acc2 = __builtin_amdgcn_mfma_f32_16x16x32_bf16(he, wf2[kt], acc2, 0, 0, 0);
        }
        L2EW(511);
    }
}

__global__ __launch_bounds__(512, 1)
void lstm_main(const u16* __restrict__ xg,
               const u16* __restrict__ whhf,
               const float* __restrict__ w_ih2,
               const float* __restrict__ w_hh2,
               const float* __restrict__ b_ih2,
               const float* __restrict__ b_hh2,
               float* __restrict__ out) {
    __shared__ __align__(16) u16 wlds[10 * 3584]; // 71,680 B: LDS B-frag tiles
    __shared__ __align__(16) u16 hbuf[2 * 224];   //    896 B: dbuf'd h (row 0)
    __shared__ __align__(16) u16 xgs[2 * 832];    //  3,328 B: staged xg (dbuf)
    __shared__ char ldspad[8192];                 // total ~84 KB -> 1 WG/CU

    int tid = threadIdx.x, mw = blockIdx.x;
    int l = tid & 63, wv = tid >> 6;

    for (int i = tid; i < 448; i += 512) hbuf[i] = 0;
    ((volatile char*)ldspad)[tid] = 0; // keep pad alive
    // preload LDS weight tiles: slot s = w*2+q holds tile (2w+1) + 13*(2+q)
    // (group B gates g,o for heavy waves w=0..4)
    for (int i = tid; i < 10 * 448; i += 512) {
        int s = i / 448, off = i - s * 448;
        int T = (2 * (s >> 1) + 1) + 13 * (2 + (s & 1));
        ((uint4*)wlds)[s * 448 + off] = ((const uint4*)whhf)[(size_t)T * 448 + off];
    }
    __syncthreads();

    // w0-4: groups {2w, 2w+1} (B gates g,o from LDS slots 2w,2w+1)
    // w5,w6: groups 10,11 + stage half-rows; w7: group 12 + layer-2
    if (wv < 5)
        lstm_body<0>(2 * wv, 2 * wv + 1, wv * 2, 0, l, mw, xg, whhf, w_ih2, w_hh2, b_ih2, b_hh2, out, hbuf, xgs, wlds);
    else if (wv < 7)
        lstm_body<1>(10 + (wv - 5), 0, 0, (wv - 5) * 832, l, mw, xg, whhf, w_ih2, w_hh2, b_ih2, b_hh2, out, hbuf, xgs, wlds);
    else
        lstm_body<2>(12, 0, 0, 0, l, mw, xg, whhf, w_ih2, w_hh2, b_ih2, b_hh2, out, hbuf, xgs, wlds);
}

extern "C" void kernel_launch(void* const* d_in, const int* in_sizes, int n_in,
                              void* d_out, int out_size, void* d_ws, size_t ws_size,
                              hipStream_t stream) {
    const float* X = (const float*)d_in[0];
    const float* w_ih1 = (const float*)d_in[1];
    const float* w_hh1 = (const float*)d_in[2];
    const float* b_ih1 = (const float*)d_in[3];
    const float* b_hh1 = (const float*)d_in[4];
    const float* w_ih2 = (const float*)d_in[5];
    const float* w_hh2 = (const float*)d_in[6];
    const float* b_ih2 = (const float*)d_in[7];
    const float* b_hh2 = (const float*)d_in[8];
    float* out = (float*)d_out;

    char* ws = (char*)d_ws;
    size_t off = 0;
    u16* xg = (u16*)(ws + off);
    off += (size_t)512 * 256 * G1P * 2; // 218,103,808 B
    u16* whhf = (u16*)(ws + off);
    off += (size_t)23296 * 8 * 2; // 372,736 B (also absorbs t=512 stage overread)
    u16* wihf = (u16*)(ws + off);
    off += (size_t)13312 * 8 * 2; // 212,992 B
    float* b1p = (float*)(ws + off);
    off += G1P * 4;
    if (ws_size < off) return; // insufficient workspace -> visible failure

    repack_k<<<143, 256, 0, stream>>>(w_ih1, w_hh1, b_ih1, b_hh1, wihf, whhf, b1p);
    xg_gemm<<<2048, 256, 0, stream>>>(X, wihf, b1p, xg);
    lstm_main<<<256, 512, 0, stream>>>(xg, whhf, w_ih2, w_hh2, b_ih2, b_hh2, out);
}